// Round 4
// baseline (4764.042 us; speedup 1.0000x reference)
//
#include <hip/hip_runtime.h>

#define XD    64      // x_dim
#define HID   256     // hidden
#define G4    1024    // 4*hidden
#define TLEN  2048
#define BATCH 64
#define NPART 8       // blocks per chain-group
#define NGRP  32      // chain groups; each group serves 2 chains (A,B)
#define UPB   32      // hidden units per part
#define CPB   128     // gate columns per part (4 gates x 32 units)
#define TSTRIDE 16    // ints between groups' handshake-token lines (64B)

typedef unsigned int uint;

__device__ __forceinline__ float sigmf(float x) {
    return 1.0f / (1.0f + __expf(-x));
}
// tanh(x) = 1 - 2/(exp(2x)+1); __expf saturation gives correct +/-1 tails
__device__ __forceinline__ float tanhfast(float x) {
    return 1.0f - 2.0f / (1.0f + __expf(2.0f * x));
}

// ---- fused (h, stamp) 8-byte pair transport ----------------------------
// fast path (parts verified same-XCD): sc0 = bypass CU L1, coherent at the
// shared per-XCD L2. nt: never allocate in L1 so polls can't go stale.
__device__ __forceinline__ uint2 ld_pair_sc0(const uint2* p) {
    uint2 r;
    asm volatile("global_load_dwordx2 %0, %1, off sc0 nt\n\ts_waitcnt vmcnt(0)"
                 : "=v"(r) : "v"(p) : "memory");
    return r;
}
__device__ __forceinline__ void st_pair_sc0(uint2* p, uint2 v) {
    asm volatile("global_store_dwordx2 %0, %1, off sc0" :: "v"(p), "v"(v) : "memory");
}
// slow path (parts on different XCDs): device-scope 8B atomics via LLC.
__device__ __forceinline__ uint2 ld_pair_dev(const uint2* p) {
    unsigned long long u = __hip_atomic_load((const unsigned long long*)p,
                                             __ATOMIC_RELAXED, __HIP_MEMORY_SCOPE_AGENT);
    uint2 r; r.x = (uint)(u & 0xffffffffu); r.y = (uint)(u >> 32); return r;
}
__device__ __forceinline__ void st_pair_dev(uint2* p, uint2 v) {
    unsigned long long u = ((unsigned long long)v.y << 32) | (unsigned long long)v.x;
    __hip_atomic_store((unsigned long long*)p, u, __ATOMIC_RELAXED, __HIP_MEMORY_SCOPE_AGENT);
}

// Zero pair stamps (both buffers) + handshake tokens. ws is re-poisoned to
// 0xAA before every timed call, so this must run every launch.
__global__ void init_ws(unsigned long long* __restrict__ pairs, int* __restrict__ tok) {
    const int i = blockIdx.x * 256 + threadIdx.x;       // 64 blocks x 256 thr
    pairs[i] = 0ULL;                                    // buffer 0
    pairs[BATCH * HID + i] = 0ULL;                      // buffer 1
    if (threadIdx.x < TSTRIDE) tok[blockIdx.x * TSTRIDE + threadIdx.x] = 0;
}

// 256 blocks = 32 groups x 8 parts, 256 threads, 1 block/CU.
// Group-major decode: grp = blk&31, part = blk>>5 -> all 8 parts of a group
// share blk%8 (32 = 0 mod 8) -> same XCD under round-robin dispatch
// (runtime handshake verifies; device-scope fallback if not).
//
// NEW vs r3: TWO chains per group, steps interleaved. While chain A's publish
// propagates through L2 and its next h is in flight, the block computes chain
// B's step (and vice versa). Each publish gets ~a half-round (~600cy) before
// its consumer polls -> first-try poll hits; sync latency leaves the critical
// path. Gate phases overlap the *other* chain's poll/stage (gatesB overlaps
// next round's pollA: no barrier between them).
//
// Per-thread compute core unchanged from r3 (4-column reuse):
// thread (slice s = tid>>5, quad cq = tid&31) owns output columns 4cq..4cq+3
// and operand elements [40s, 40s+40); 10 ds_read_b128 + 160 FMA per chain.
__global__ __launch_bounds__(256, 1)
void lstm_par(const float* __restrict__ x,     // (B, T, 64)
              const float* __restrict__ wih,   // (1024, 64) row-major
              const float* __restrict__ whh,   // (1024, 256) row-major
              const float* __restrict__ bias,  // (1024)
              float* __restrict__ out,         // (B, T, 256)
              uint2* __restrict__ pairs,       // (2, B, 256) {h_bits, stamp}
              int* __restrict__ tok)           // (B, TSTRIDE) handshake tokens
{
    const int grp  = blockIdx.x & 31;          // chain group
    const int part = blockIdx.x >> 5;          // part
    const int cA   = grp * 2;                  // chain A (batch index)
    const int cB   = grp * 2 + 1;              // chain B
    const int tid  = threadIdx.x;
    const int lane = tid & 63;
    const int wv   = tid >> 6;                 // wave 0..3
    const int s    = tid >> 5;                 // operand slice 0..7 (40 elems)
    const int cq   = tid & 31;                 // column quad: cols 4cq..4cq+3

    __shared__ __align__(16) float vecA[XD + HID], vecB[XD + HID];
    __shared__ __align__(16) float zpA[4][CPB], zpB[4][CPB];
    __shared__ int fastsh;

    // ---- one-time: transposed weights into registers (shared by A and B) ----
    // w4[e] = weights of the thread's 4 columns at combined-element 40s+e.
    float4 w4[40];
    {
        int jr[4];
        #pragma unroll
        for (int k = 0; k < 4; ++k) {
            const int c = 4 * cq + k;                       // col within part
            jr[k] = (c >> 5) * 256 + part * UPB + (c & 31); // global gate row
        }
        #pragma unroll
        for (int e = 0; e < 40; ++e) {
            const int ge = s * 40 + e;                      // 0..319
            float v0, v1, v2, v3;
            if (ge < XD) {
                v0 = wih[jr[0] * XD + ge]; v1 = wih[jr[1] * XD + ge];
                v2 = wih[jr[2] * XD + ge]; v3 = wih[jr[3] * XD + ge];
            } else {
                const int he = ge - XD;
                v0 = whh[jr[0] * HID + he]; v1 = whh[jr[1] * HID + he];
                v2 = whh[jr[2] * HID + he]; v3 = whh[jr[3] * HID + he];
            }
            w4[e] = make_float4(v0, v1, v2, v3);
        }
    }
    // gate-wave bias preload (threads 0..31: unit u = tid)
    float bi = 0.f, bf = 0.f, bg = 0.f, bo = 0.f;
    if (tid < UPB) {
        const int gj = part * UPB + tid;
        bi = bias[gj]; bf = bias[256 + gj]; bg = bias[512 + gj]; bo = bias[768 + gj];
    }

    // ---- one-time XCD co-location handshake (device-scope, reliable) ----
    {
        int xcc;
        asm volatile("s_getreg_b32 %0, hwreg(HW_REG_XCC_ID)" : "=s"(xcc));
        xcc &= 15;
        int* tb = tok + grp * TSTRIDE;
        if (tid == 0)
            __hip_atomic_store(tb + part, 256 + xcc, __ATOMIC_RELEASE,
                               __HIP_MEMORY_SCOPE_AGENT);
        if (tid < 64) {
            const int ln = tid & 7;            // 64 lanes cover 8 tokens
            int v = 0, guard = 0;
            for (;;) {
                v = __hip_atomic_load(tb + ln, __ATOMIC_RELAXED,
                                      __HIP_MEMORY_SCOPE_AGENT);
                if (__all(v >= 256)) break;
                __builtin_amdgcn_s_sleep(2);
                if (++guard > 200000) break;   // catastrophe-only
            }
            const int ok = __all(v >= 256);
            const int v0 = __shfl(v, 0);
            const int eq = (ok && __all(v == v0)) ? 1 : 0;
            if (tid == 0) fastsh = eq;
        }
        __syncthreads();
    }
    const bool fast = (fastsh != 0);

    uint2* __restrict__ pA0 = pairs + (size_t)cA * HID;
    uint2* __restrict__ pA1 = pairs + (size_t)(BATCH + cA) * HID;
    uint2* __restrict__ pB0 = pairs + (size_t)cB * HID;
    uint2* __restrict__ pB1 = pairs + (size_t)(BATCH + cB) * HID;
    const float* __restrict__ xbA = x + (size_t)cA * TLEN * XD;
    const float* __restrict__ xbB = x + (size_t)cB * TLEN * XD;
    float* __restrict__ obA = out + (size_t)cA * TLEN * HID;
    float* __restrict__ obB = out + (size_t)cB * TLEN * HID;

    float cstA = 0.0f, cstB = 0.0f;   // thread tid<32 owns cell of unit tid
    float xregA = (tid < XD) ? xbA[tid] : 0.0f;
    float xregB = (tid < XD) ? xbB[tid] : 0.0f;

    // poll chain's pair (stamp == t rides with the data), stage into LDS vec
    #define POLLSTAGE(P0, P1, VEC, XREG) do {                                 \
        if (t > 0) {                                                          \
            const uint2* src = ((t & 1) ? (P0) : (P1)) + tid;                 \
            uint2 pr; int it = 0;                                             \
            for (;;) {                                                        \
                pr = (fast && it < 4096) ? ld_pair_sc0(src) : ld_pair_dev(src);\
                if (pr.y == (uint)t) break;  /* exact-match: deadlock over */ \
                __builtin_amdgcn_s_sleep(1); /* silent staleness           */ \
                if (++it > 100000) break;    /* hang-guard                 */ \
            }                                                                 \
            (VEC)[XD + tid] = __uint_as_float(pr.x);                          \
        } else {                                                              \
            (VEC)[XD + tid] = 0.0f;                                           \
        }                                                                     \
        if (tid < XD) (VEC)[tid] = (XREG);                                    \
    } while (0)

    // 40-element slice x 4 columns: 10 ds_read_b128, 160 FMA, pair-reduce
    #define COMPUTE(VEC, ZP) do {                                             \
        float4 acc = make_float4(0.f, 0.f, 0.f, 0.f);                         \
        const float4* vb = (const float4*)((VEC) + 40 * s);                   \
        _Pragma("unroll")                                                     \
        for (int i = 0; i < 10; ++i) {                                        \
            const float4 v = vb[i];                                           \
            acc.x = fmaf(w4[4*i+0].x, v.x, acc.x);                            \
            acc.y = fmaf(w4[4*i+0].y, v.x, acc.y);                            \
            acc.z = fmaf(w4[4*i+0].z, v.x, acc.z);                            \
            acc.w = fmaf(w4[4*i+0].w, v.x, acc.w);                            \
            acc.x = fmaf(w4[4*i+1].x, v.y, acc.x);                            \
            acc.y = fmaf(w4[4*i+1].y, v.y, acc.y);                            \
            acc.z = fmaf(w4[4*i+1].z, v.y, acc.z);                            \
            acc.w = fmaf(w4[4*i+1].w, v.y, acc.w);                            \
            acc.x = fmaf(w4[4*i+2].x, v.z, acc.x);                            \
            acc.y = fmaf(w4[4*i+2].y, v.z, acc.y);                            \
            acc.z = fmaf(w4[4*i+2].z, v.z, acc.z);                            \
            acc.w = fmaf(w4[4*i+2].w, v.z, acc.w);                            \
            acc.x = fmaf(w4[4*i+3].x, v.w, acc.x);                            \
            acc.y = fmaf(w4[4*i+3].y, v.w, acc.y);                            \
            acc.z = fmaf(w4[4*i+3].z, v.w, acc.z);                            \
            acc.w = fmaf(w4[4*i+3].w, v.w, acc.w);                            \
        }                                                                     \
        acc.x += __shfl_xor(acc.x, 32);                                       \
        acc.y += __shfl_xor(acc.y, 32);                                       \
        acc.z += __shfl_xor(acc.z, 32);                                       \
        acc.w += __shfl_xor(acc.w, 32);                                       \
        if (lane < 32) *(float4*)(&(ZP)[wv][4 * lane]) = acc;                 \
    } while (0)

    // gates + state update + fused publish (threads 0..31, wave 0)
    #define GATES(ZP, CST, P0, P1, OB) do {                                   \
        if (tid < UPB) {                                                      \
            float zi = bi, zf = bf, zg = bg, zo = bo;                         \
            _Pragma("unroll")                                                 \
            for (int w2 = 0; w2 < 4; ++w2) {                                  \
                zi += (ZP)[w2][tid];                                          \
                zf += (ZP)[w2][32 + tid];                                     \
                zg += (ZP)[w2][64 + tid];                                     \
                zo += (ZP)[w2][96 + tid];                                     \
            }                                                                 \
            const float ig = sigmf(zi);                                       \
            const float fg = sigmf(zf);                                       \
            const float gg = tanhfast(zg);                                    \
            const float og = sigmf(zo);                                       \
            (CST) = fg * (CST) + ig * gg;                                     \
            const float h = og * tanhfast(CST);                               \
            uint2 pv; pv.x = __float_as_uint(h); pv.y = (uint)(t + 1);        \
            uint2* dst = ((t & 1) ? (P1) : (P0)) + part * UPB + tid;          \
            if (fast) st_pair_sc0(dst, pv);                                   \
            else      st_pair_dev(dst, pv);                                   \
            (OB)[(size_t)t * HID + part * UPB + tid] = h;                     \
        }                                                                     \
    } while (0)

    for (int t = 0; t < TLEN; ++t) {
        // -- chain A: poll/stage (overlapped previous round's gatesB) --
        POLLSTAGE(pA0, pA1, vecA, xregA);
        __syncthreads();                                   // BAR1
        if (t + 1 < TLEN && tid < XD)
            xregA = xbA[(size_t)(t + 1) * XD + tid];       // prefetch next x_A
        COMPUTE(vecA, zpA);
        __syncthreads();                                   // BAR2
        // -- gatesA (wave0) runs WHILE all threads poll/stage chain B --
        GATES(zpA, cstA, pA0, pA1, obA);
        POLLSTAGE(pB0, pB1, vecB, xregB);
        __syncthreads();                                   // BAR3
        if (t + 1 < TLEN && tid < XD)
            xregB = xbB[(size_t)(t + 1) * XD + tid];       // prefetch next x_B
        COMPUTE(vecB, zpB);
        __syncthreads();                                   // BAR4
        // -- gatesB overlaps next round's pollA (no barrier in between) --
        GATES(zpB, cstB, pB0, pB1, obB);
    }
    #undef POLLSTAGE
    #undef COMPUTE
    #undef GATES
}

extern "C" void kernel_launch(void* const* d_in, const int* in_sizes, int n_in,
                              void* d_out, int out_size, void* d_ws, size_t ws_size,
                              hipStream_t stream) {
    const float* x    = (const float*)d_in[0];
    const float* wih  = (const float*)d_in[1];
    const float* whh  = (const float*)d_in[2];
    const float* bias = (const float*)d_in[3];
    float* out = (float*)d_out;

    uint2* pairs = (uint2*)d_ws;  // 2*64*256 pairs = 256 KB
    int*   tok   = (int*)((char*)d_ws + (size_t)2 * BATCH * HID * sizeof(uint2)); // 4 KB

    hipLaunchKernelGGL(init_ws, dim3(BATCH), dim3(256), 0, stream,
                       (unsigned long long*)d_ws, tok);
    hipLaunchKernelGGL(lstm_par, dim3(NGRP * NPART), dim3(256), 0, stream,
                       x, wih, whh, bias, out, pairs, tok);
}

// Round 5
// 2820.675 us; speedup vs baseline: 1.6890x; 1.6890x over previous
//
#include <hip/hip_runtime.h>

#define XD    64      // x_dim
#define HID   256     // hidden
#define G4    1024    // 4*hidden
#define TLEN  2048
#define BATCH 64
#define NPART 8       // blocks per chain
#define UPB   32      // hidden units per part
#define CPB   128     // gate columns per part (4 gates x 32 units)
#define TSTRIDE 16    // ints between chains' handshake-token lines (64B)

typedef unsigned int uint;

__device__ __forceinline__ float sigmf(float x) {
    return 1.0f / (1.0f + __expf(-x));
}
// tanh(x) = 1 - 2/(exp(2x)+1); __expf saturation gives correct +/-1 tails
__device__ __forceinline__ float tanhfast(float x) {
    return 1.0f - 2.0f / (1.0f + __expf(2.0f * x));
}

// ---- fused (h, stamp) 8-byte pair transport ----------------------------
// fast path (parts verified same-XCD): sc0 = bypass CU L1, coherent at the
// shared per-XCD L2. nt: never allocate in L1 so polls can't go stale.
__device__ __forceinline__ uint2 ld_pair_sc0(const uint2* p) {
    uint2 r;
    asm volatile("global_load_dwordx2 %0, %1, off sc0 nt\n\ts_waitcnt vmcnt(0)"
                 : "=v"(r) : "v"(p) : "memory");
    return r;
}
__device__ __forceinline__ void st_pair_sc0(uint2* p, uint2 v) {
    asm volatile("global_store_dwordx2 %0, %1, off sc0" :: "v"(p), "v"(v) : "memory");
}
// slow path (parts on different XCDs): device-scope 8B atomics via LLC.
__device__ __forceinline__ uint2 ld_pair_dev(const uint2* p) {
    unsigned long long u = __hip_atomic_load((const unsigned long long*)p,
                                             __ATOMIC_RELAXED, __HIP_MEMORY_SCOPE_AGENT);
    uint2 r; r.x = (uint)(u & 0xffffffffu); r.y = (uint)(u >> 32); return r;
}
__device__ __forceinline__ void st_pair_dev(uint2* p, uint2 v) {
    unsigned long long u = ((unsigned long long)v.y << 32) | (unsigned long long)v.x;
    __hip_atomic_store((unsigned long long*)p, u, __ATOMIC_RELAXED, __HIP_MEMORY_SCOPE_AGENT);
}

// Zero pair stamps (both buffers) + handshake tokens. ws is re-poisoned to
// 0xAA before every timed call, so this must run every launch.
__global__ void init_ws(unsigned long long* __restrict__ pairs, int* __restrict__ tok) {
    const int i = blockIdx.x * 256 + threadIdx.x;       // 64 blocks x 256 thr
    pairs[i] = 0ULL;                                    // buffer 0
    pairs[BATCH * HID + i] = 0ULL;                      // buffer 1
    if (threadIdx.x < TSTRIDE) tok[blockIdx.x * TSTRIDE + threadIdx.x] = 0;
}

// 512 blocks = 64 chains x 8 parts, 256 threads, 2 blocks/CU.
// Decode: part = (blk>>3)&7, chain = (blk&7) + 8*(blk>>6).
//  - XCD(blk) = blk&7 = chain&7: all 8 parts of a chain share one XCD
//    (runtime handshake verifies; device-scope fallback if not).
//  - Within an XCD, ascending-blk fill order puts chains g and g+4 (g=chain>>3)
//    into the two slots of each CU -> co-resident blocks are from DIFFERENT
//    chains. A one-time half-step stagger for g>=4 anti-phases them: one block
//    computes while its CU-mate polls (hardware latency hiding, no barriers
//    shared across chains -- the r4 mistake). Mapping guess is speed-only.
//
// Per-thread compute core (r3, 4-column reuse): thread (slice s = tid>>5,
// quad cq = tid&31) owns output columns 4cq..4cq+3 and operand elements
// [40s, 40s+40); 10 ds_read_b128 + 160 FMA per step.
__global__ __launch_bounds__(256, 2)
void lstm_par(const float* __restrict__ x,     // (B, T, 64)
              const float* __restrict__ wih,   // (1024, 64) row-major
              const float* __restrict__ whh,   // (1024, 256) row-major
              const float* __restrict__ bias,  // (1024)
              float* __restrict__ out,         // (B, T, 256)
              uint2* __restrict__ pairs,       // (2, B, 256) {h_bits, stamp}
              int* __restrict__ tok)           // (B, TSTRIDE) handshake tokens
{
    const int blk  = blockIdx.x;
    const int part = (blk >> 3) & 7;
    const int b    = (blk & 7) + 8 * (blk >> 6);   // chain
    const int tid  = threadIdx.x;
    const int lane = tid & 63;
    const int wv   = tid >> 6;                 // wave 0..3
    const int s    = tid >> 5;                 // operand slice 0..7 (40 elems)
    const int cq   = tid & 31;                 // column quad: cols 4cq..4cq+3

    __shared__ __align__(16) float vec[XD + HID]; // [x_t | h_{t-1}]
    __shared__ __align__(16) float zp[4][CPB];    // per-wave z partials
    __shared__ int fastsh;

    // ---- one-time: transposed weights into registers ----
    // w4[e] = weights of the thread's 4 columns at combined-element 40s+e.
    float4 w4[40];
    {
        int jr[4];
        #pragma unroll
        for (int k = 0; k < 4; ++k) {
            const int c = 4 * cq + k;                       // col within part
            jr[k] = (c >> 5) * 256 + part * UPB + (c & 31); // global gate row
        }
        #pragma unroll
        for (int e = 0; e < 40; ++e) {
            const int ge = s * 40 + e;                      // 0..319
            float v0, v1, v2, v3;
            if (ge < XD) {
                v0 = wih[jr[0] * XD + ge]; v1 = wih[jr[1] * XD + ge];
                v2 = wih[jr[2] * XD + ge]; v3 = wih[jr[3] * XD + ge];
            } else {
                const int he = ge - XD;
                v0 = whh[jr[0] * HID + he]; v1 = whh[jr[1] * HID + he];
                v2 = whh[jr[2] * HID + he]; v3 = whh[jr[3] * HID + he];
            }
            w4[e] = make_float4(v0, v1, v2, v3);
        }
    }
    // split-gate bias preload: lane u (tid<32): zi,zg; lane 32+u: zf,zo.
    float b1 = 0.f, b2 = 0.f;
    if (tid < 64) {
        const int u  = tid & 31;
        const int pu = part * UPB + u;
        if (tid < 32) { b1 = bias[pu];       b2 = bias[512 + pu]; } // i, g
        else          { b1 = bias[256 + pu]; b2 = bias[768 + pu]; } // f, o
    }

    // ---- one-time XCD co-location handshake (device-scope, reliable) ----
    {
        int xcc;
        asm volatile("s_getreg_b32 %0, hwreg(HW_REG_XCC_ID)" : "=s"(xcc));
        xcc &= 15;
        int* tb = tok + b * TSTRIDE;
        if (tid == 0)
            __hip_atomic_store(tb + part, 256 + xcc, __ATOMIC_RELEASE,
                               __HIP_MEMORY_SCOPE_AGENT);
        if (tid < 64) {
            const int ln = tid & 7;            // 64 lanes cover 8 tokens
            int v = 0, guard = 0;
            for (;;) {
                v = __hip_atomic_load(tb + ln, __ATOMIC_RELAXED,
                                      __HIP_MEMORY_SCOPE_AGENT);
                if (__all(v >= 256)) break;
                __builtin_amdgcn_s_sleep(2);
                if (++guard > 200000) break;   // catastrophe-only
            }
            const int ok = __all(v >= 256);
            const int v0 = __shfl(v, 0);
            const int eq = (ok && __all(v == v0)) ? 1 : 0;
            if (tid == 0) fastsh = eq;
        }
        __syncthreads();
    }
    const bool fast = (fastsh != 0);

    // ---- one-time anti-phase stagger (~half a step) for chain-group g>=4:
    // co-resident CU-mate (group g-4) runs a half-step ahead, so its compute
    // overlaps our poll and vice versa. Pure heuristic; zero correctness risk.
    if ((b >> 3) >= 4) {
        __builtin_amdgcn_s_sleep(15);          // ~960 cy
        __builtin_amdgcn_s_sleep(10);          // ~640 cy
    }

    uint2* __restrict__ pb0 = pairs + (size_t)b * HID;            // buffer 0
    uint2* __restrict__ pb1 = pairs + (size_t)(BATCH + b) * HID;  // buffer 1
    const float* __restrict__ xb = x + (size_t)b * TLEN * XD;
    float* __restrict__ ob = out + (size_t)b * TLEN * HID;

    float cst = 0.0f;                     // thread tid<32 owns cell of unit tid
    float xreg = (tid < XD) ? xb[tid] : 0.0f;   // x_0 prefetch

    for (int t = 0; t < TLEN; ++t) {
        // ---- gather h_{t-1}: each thread polls ITS fused pair (stamp rides
        // with the data: one L2 leg) then stages into LDS. Tight spin first
        // 64 iters (~200cy granularity), then sleep-spin.
        if (t > 0) {
            const uint2* src = ((t & 1) ? pb0 : pb1) + tid;  // buf (t-1)&1
            uint2 pr;
            int it = 0;
            for (;;) {
                pr = (fast && it < 4096) ? ld_pair_sc0(src) : ld_pair_dev(src);
                if (pr.y == (uint)t) break;   // exact-match: deadlock (visible
                if (++it > 64) __builtin_amdgcn_s_sleep(1);  // failure) over
                if (it > 100000) break;       // staleness; hang-guard
            }
            vec[XD + tid] = __uint_as_float(pr.x);
        } else {
            vec[XD + tid] = 0.0f;             // h_{-1} = 0
        }
        if (tid < XD) vec[tid] = xreg;
        __syncthreads(); // (B) -- also protects vec/zp from next-step overwrite

        // prefetch next x (latency overlapped by compute + next poll)
        if (t + 1 < TLEN && tid < XD) xreg = xb[(size_t)(t + 1) * XD + tid];

        // ---- 40-element slice x 4 columns: 10 ds_read_b128, 160 FMA ----
        float4 acc = make_float4(0.f, 0.f, 0.f, 0.f);
        const float4* vb = (const float4*)(vec + 40 * s);
        #pragma unroll
        for (int i = 0; i < 10; ++i) {
            const float4 v = vb[i];
            #define FMA1(R, VE)                              \
                acc.x = fmaf(w4[4*i + R].x, (VE), acc.x);    \
                acc.y = fmaf(w4[4*i + R].y, (VE), acc.y);    \
                acc.z = fmaf(w4[4*i + R].z, (VE), acc.z);    \
                acc.w = fmaf(w4[4*i + R].w, (VE), acc.w);
            FMA1(0, v.x) FMA1(1, v.y) FMA1(2, v.z) FMA1(3, v.w)
            #undef FMA1
        }
        // combine slice pairs (lane l <-> l^32 hold slices 2wv, 2wv+1)
        acc.x += __shfl_xor(acc.x, 32);
        acc.y += __shfl_xor(acc.y, 32);
        acc.z += __shfl_xor(acc.z, 32);
        acc.w += __shfl_xor(acc.w, 32);
        if (lane < 32) *(float4*)(&zp[wv][4 * lane]) = acc;
        __syncthreads(); // (C)

        // ---- split gates across wave 0's 64 lanes:
        // lane u: zi, zg -> ig, gg;  lane 32+u: zf, zo -> fg, og;
        // two shfl_xor(32) bring fg,og to lane u, which owns cell state c.
        if (tid < 64) {
            float z1 = b1, z2 = b2;
            #pragma unroll
            for (int w2 = 0; w2 < 4; ++w2) {
                z1 += zp[w2][tid];            // col tid      (i or f region)
                z2 += zp[w2][64 + tid];       // col 64+tid   (g or o region)
            }
            const float g1 = sigmf(z1);                          // ig | fg
            const float g2 = (tid < 32) ? tanhfast(z2) : sigmf(z2); // gg | og
            const float gf = __shfl_xor(g1, 32);  // lane u receives fg
            const float go = __shfl_xor(g2, 32);  // lane u receives og
            if (tid < UPB) {
                cst = gf * cst + g1 * g2;
                const float h = go * tanhfast(cst);
                // fused publish: stamp travels WITH the value (single 8B store)
                uint2 pv; pv.x = __float_as_uint(h); pv.y = (uint)(t + 1);
                uint2* dst = ((t & 1) ? pb1 : pb0) + part * UPB + tid;
                if (fast) st_pair_sc0(dst, pv);
                else      st_pair_dev(dst, pv);
                // output store AFTER the publish: off the critical path
                ob[(size_t)t * HID + part * UPB + tid] = h;
            }
        }
    }
}

extern "C" void kernel_launch(void* const* d_in, const int* in_sizes, int n_in,
                              void* d_out, int out_size, void* d_ws, size_t ws_size,
                              hipStream_t stream) {
    const float* x    = (const float*)d_in[0];
    const float* wih  = (const float*)d_in[1];
    const float* whh  = (const float*)d_in[2];
    const float* bias = (const float*)d_in[3];
    float* out = (float*)d_out;

    uint2* pairs = (uint2*)d_ws;  // 2*64*256 pairs = 256 KB
    int*   tok   = (int*)((char*)d_ws + (size_t)2 * BATCH * HID * sizeof(uint2)); // 4 KB

    hipLaunchKernelGGL(init_ws, dim3(BATCH), dim3(256), 0, stream,
                       (unsigned long long*)d_ws, tok);
    hipLaunchKernelGGL(lstm_par, dim3(BATCH * NPART), dim3(256), 0, stream,
                       x, wih, whh, bias, out, pairs, tok);
}